// Round 11
// baseline (72.234 us; speedup 1.0000x reference)
//
#include <hip/hip_runtime.h>
#include <hip/hip_bf16.h>

#define B_TOTAL 65536
#define NR 4
#define VD 100
#define HD 200
#define DK 32
#define MH 128
#define RD 64

typedef __attribute__((ext_vector_type(8))) short bf16x8;
typedef __attribute__((ext_vector_type(4))) float f32x4;
typedef __attribute__((ext_vector_type(2))) double f64x2;

static __device__ inline unsigned short f2bf(float x) {
    __hip_bfloat16 h = __float2bfloat16(x);
    return __builtin_bit_cast(unsigned short, h);
}

// ---- workspace layout (bytes) ----
#define WS_GC    0         // 1600 * 8 = 12800 (packed G, block-sparse form)
#define WS_CNT   19200     // 16
#define WS_LIST  19456     // 4 * 65536 * 2 = 524288
#define WS_VB    543744    // 65536
#define WS_W1F   609280    // 229376
#define WS_W2F   838656    // 114688

// ---------------- kernel 0a: packed G (fp64) + zero counters ----------------
// score(r,v) = dot(h[v], A[v][r]) + dot(h[2], B[v][r]).
// Gc[dd][c]: c = isB*8 + v*4 + r ; A at c<8, B at c>=8. K per score: 200.
__global__ __launch_bounds__(256) void k0_prep(
    const float* __restrict__ rule_emb, const float* __restrict__ Wq,
    const float* __restrict__ bq, const float* __restrict__ Wk,
    double* __restrict__ Gc, int* __restrict__ cnt)
{
    int tid = threadIdx.x;
    if (tid < NR) cnt[tid] = 0;

    __shared__ double readS[NR * DK];
    if (tid < NR * DK) {
        int r = tid >> 5, k = tid & 31;
        double a = (double)bq[k];
        for (int d = 0; d < RD; ++d)
            a += (double)rule_emb[r * RD + d] * (double)Wq[d * DK + k];
        readS[tid] = a;
    }
    __syncthreads();

    for (int idx = tid; idx < 100 * 16; idx += 256) {
        int dd = idx >> 4, c = idx & 15;
        int isB = (c >> 3) & 1, v = (c >> 2) & 1, r = c & 3;
        int row = v * HD + isB * 100 + dd;
        double g = 0.0;
        for (int k = 0; k < DK; ++k)
            g += (double)Wk[row * DK + k] * readS[r * DK + k];
        Gc[idx] = g;   // layout Gc[dd*16 + c]
    }
}

// ---------------- kernel 0b: W1/W2 -> bf16 MFMA B-fragment layout ----------------
__global__ __launch_bounds__(256) void k0_wfrag(
    const float* __restrict__ W1, const float* __restrict__ W2,
    unsigned short* __restrict__ W1f, unsigned short* __restrict__ W2f)
{
    int i = blockIdx.x * 256 + threadIdx.x;
    if (i < 114688) {
        int r = i / 28672, rem = i % 28672;
        int ks = rem / 4096, rem2 = rem % 4096;
        int n = rem2 >> 9, l = (rem2 >> 3) & 63, j = rem2 & 7;
        int k = ks * 32 + ((l >> 4) << 3) + j;
        int c = n * 16 + (l & 15);
        float v = (k < HD) ? W1[((size_t)r * HD + k) * MH + c] : 0.f;
        W1f[i] = f2bf(v);
    } else if (i < 114688 + 57344) {
        int t = i - 114688;
        int r = t / 14336, rem = t % 14336;
        int ks = rem / 3584, rem2 = rem % 3584;
        int n = rem2 >> 9, l = (rem2 >> 3) & 63, j = rem2 & 7;
        int k = ks * 32 + ((l >> 4) << 3) + j;
        int c = n * 16 + (l & 15);
        float v = (c < VD) ? W2[((size_t)r * MH + k) * VD + c] : 0.f;
        W2f[t] = f2bf(v);
    }
}

// ---------------- kernel 1: selection (fp64) + bucket compaction ----------------
// v7: R7's proven structure (contiguous per-thread rows, FETCH 42MB, 15-deep
// h batches) + packed block-sparse G loaded as double2 (b128, per-lane
// uniform, L1-resident 12.8KB). Ladder evidence: every prior variant had
// G-load:FMA = 1:1 (R7 2400 loads = 42us; R9 LDS = 62; R10 as(4) = 49) --
// the cost IS the G-load issue count. v7 cuts it 2400 -> 800 instrs/elem
// (2 loads per 4 FMAs seg0/1, 4 per 8 seg2). Per-acc accumulation order
// identical to R9/R10 (ascending dd) -> bit-identical argmax (proven).
__global__ __launch_bounds__(256) void k1_select(
    const float* __restrict__ hidden, const double* __restrict__ Gc,
    int* __restrict__ cnt, unsigned short* __restrict__ list16,
    unsigned char* __restrict__ vbyte)
{
    __shared__ int lcnt[NR];
    __shared__ int lbase[NR];
    int tid = threadIdx.x;
    if (tid < NR) lcnt[tid] = 0;
    __syncthreads();

    int b = blockIdx.x * 256 + tid;
    const float4* h4 = (const float4*)(hidden + (size_t)b * 300);
    const f64x2* G2 = (const f64x2*)Gc;   // f64x2 index: dd*8 + c/2

    double acc[16];
#pragma unroll
    for (int c = 0; c < 16; ++c) acc[c] = 0.0;

    for (int c0 = 0; c0 < 75; c0 += 15) {
        float4 hv[15];
#pragma unroll
        for (int u = 0; u < 15; ++u) hv[u] = h4[c0 + u];
#pragma unroll
        for (int u = 0; u < 15; ++u) {
            int ch = c0 + u;              // compile-time within unrolled body
            int seg = ch / 25;            // 0: h[0], 1: h[1], 2: h[2]
            int cc = ch - seg * 25;
            float e[4] = {hv[u].x, hv[u].y, hv[u].z, hv[u].w};
#pragma unroll
            for (int q = 0; q < 4; ++q) {
                int dd = cc * 4 + q;
                double x = (double)e[q];
                if (seg == 0) {
                    f64x2 g0 = G2[dd * 8 + 0], g1 = G2[dd * 8 + 1];
                    acc[0] = fma(x, g0[0], acc[0]);
                    acc[1] = fma(x, g0[1], acc[1]);
                    acc[2] = fma(x, g1[0], acc[2]);
                    acc[3] = fma(x, g1[1], acc[3]);
                } else if (seg == 1) {
                    f64x2 g0 = G2[dd * 8 + 2], g1 = G2[dd * 8 + 3];
                    acc[4] = fma(x, g0[0], acc[4]);
                    acc[5] = fma(x, g0[1], acc[5]);
                    acc[6] = fma(x, g1[0], acc[6]);
                    acc[7] = fma(x, g1[1], acc[7]);
                } else {
                    f64x2 g0 = G2[dd * 8 + 4], g1 = G2[dd * 8 + 5];
                    f64x2 g2 = G2[dd * 8 + 6], g3 = G2[dd * 8 + 7];
                    acc[8]  = fma(x, g0[0], acc[8]);
                    acc[9]  = fma(x, g0[1], acc[9]);
                    acc[10] = fma(x, g1[0], acc[10]);
                    acc[11] = fma(x, g1[1], acc[11]);
                    acc[12] = fma(x, g2[0], acc[12]);
                    acc[13] = fma(x, g2[1], acc[13]);
                    acc[14] = fma(x, g3[0], acc[14]);
                    acc[15] = fma(x, g3[1], acc[15]);
                }
            }
        }
    }

    // scores p = r*2+v (reshape order); first-occurrence argmax
    double sc[8];
#pragma unroll
    for (int r = 0; r < 4; ++r) {
        sc[r * 2]     = acc[r]     + acc[8 + r];
        sc[r * 2 + 1] = acc[4 + r] + acc[12 + r];
    }
    int best = 0; double bv = sc[0];
#pragma unroll
    for (int p = 1; p < 8; ++p) if (sc[p] > bv) { bv = sc[p]; best = p; }
    int r = best >> 1, v = best & 1;

    vbyte[b] = (unsigned char)v;
    int pos = atomicAdd(&lcnt[r], 1);
    __syncthreads();
    if (tid < NR) lbase[tid] = atomicAdd(&cnt[tid], lcnt[tid]);
    __syncthreads();
    list16[r * B_TOTAL + lbase[r] + pos] = (unsigned short)b;
}

// ---------------- kernel 2: bucketed bf16-MFMA MLP ----------------
// v3 (proven R9/R10: ~15us): 64-row tiles, LDS 30KB, ~5 blocks/CU;
// 4 threads/row staging with 13 batched float4.
__global__ __launch_bounds__(256) void k2_mlp(
    const float* __restrict__ hidden,
    const unsigned short* __restrict__ W1f, const unsigned short* __restrict__ W2f,
    const int* __restrict__ cnt, const unsigned short* __restrict__ list16,
    const unsigned char* __restrict__ vbyte, float* __restrict__ out)
{
    int r = blockIdx.y;
    int nb = cnt[r];
    int m0 = blockIdx.x * 64;
    if (m0 >= nb) return;
    int me = nb - m0; if (me > 64) me = 64;

    __shared__ __align__(16) unsigned short shbuf[64 * 232]; // X [64][232]; C1 overlay [64][136]
    __shared__ int ent[64];

    int tid = threadIdx.x;
    int wave = tid >> 6, lane = tid & 63;
    int lr = lane & 15, lk = lane >> 4;
    int wrow0 = wave * 16;

    if (tid < 64) {
        int idx = m0 + tid; if (idx > nb - 1) idx = nb - 1;
        int b = list16[r * B_TOTAL + idx];
        int v = vbyte[b];
        ent[tid] = (b << 1) | v;
    }
    __syncthreads();

    // stage X: thread = (e, h, t): e=tid>>2 row, h=(tid>>1)&1 seg-half,
    // t=tid&1 sub-half. 13 consecutive float4 batched into regs.
    {
        int e = tid >> 2, hh = (tid >> 1) & 1, t = tid & 1;
        int en = ent[e];
        int b = en >> 1, v = en & 1;
        int seg = hh ? (1 - v) : v;
        int q0 = t * 12;   // 0..12 / 12..24 (chunk 12 written twice, same value)
        const float4* src = (const float4*)(hidden + (size_t)b * 300 + seg * 100) + q0;
        float4 hv[13];
#pragma unroll
        for (int u = 0; u < 13; ++u) hv[u] = src[u];
#pragma unroll
        for (int u = 0; u < 13; ++u) {
            ushort4 o;
            o.x = f2bf(hv[u].x); o.y = f2bf(hv[u].y);
            o.z = f2bf(hv[u].z); o.w = f2bf(hv[u].w);
            *(ushort4*)&shbuf[e * 232 + (hh * 25 + q0 + u) * 4] = o;
        }
    }
    // zero-pad k = [200,232) fully: 4 bf16x8 chunks per row (NaN-laundering
    // hazard: stale LDS * 0-weight = NaN -> relu -> zeroed rows).
    {
        int row = tid >> 2, part = tid & 3;
        bf16x8 z = {0, 0, 0, 0, 0, 0, 0, 0};
        *(bf16x8*)&shbuf[row * 232 + 200 + part * 8] = z;
    }
    __syncthreads();

    // ---- GEMM1 ----
    const unsigned short* W1f_r = W1f + (size_t)r * 28672;
    f32x4 acc1[8];
#pragma unroll
    for (int n = 0; n < 8; ++n) acc1[n] = (f32x4){0.f, 0.f, 0.f, 0.f};

#pragma unroll
    for (int ks = 0; ks < 7; ++ks) {
        bf16x8 a0 = *(const bf16x8*)&shbuf[(wrow0 + lr) * 232 + ks * 32 + lk * 8];
#pragma unroll
        for (int n = 0; n < 8; ++n) {
            bf16x8 bfr = *(const bf16x8*)&W1f_r[(size_t)(ks * 8 + n) * 512 + lane * 8];
            acc1[n] = __builtin_amdgcn_mfma_f32_16x16x32_bf16(a0, bfr, acc1[n], 0, 0, 0);
        }
    }

    __syncthreads();  // all waves done reading X before overlay

    // relu -> bf16 -> C1 transpose-store: row=wrow0+(lane>>4)*4+j, col=n*16+(lane&15)
#pragma unroll
    for (int n = 0; n < 8; ++n)
#pragma unroll
        for (int j = 0; j < 4; ++j) {
            float v = fmaxf(acc1[n][j], 0.f);
            int row = wrow0 + lk * 4 + j;
            shbuf[row * 136 + n * 16 + lr] = f2bf(v);
        }
    __syncthreads();

    // ---- GEMM2 ----
    const unsigned short* W2f_r = W2f + (size_t)r * 14336;
    f32x4 acc2[7];
#pragma unroll
    for (int n = 0; n < 7; ++n) acc2[n] = (f32x4){0.f, 0.f, 0.f, 0.f};

#pragma unroll
    for (int ks = 0; ks < 4; ++ks) {
        bf16x8 a0 = *(const bf16x8*)&shbuf[(wrow0 + lr) * 136 + ks * 32 + lk * 8];
#pragma unroll
        for (int n = 0; n < 7; ++n) {
            bf16x8 bfr = *(const bf16x8*)&W2f_r[(size_t)(ks * 7 + n) * 512 + lane * 8];
            acc2[n] = __builtin_amdgcn_mfma_f32_16x16x32_bf16(a0, bfr, acc2[n], 0, 0, 0);
        }
    }

    // scatter-store
#pragma unroll
    for (int n = 0; n < 7; ++n) {
        int col = n * 16 + lr;
        if (col < VD) {
#pragma unroll
            for (int j = 0; j < 4; ++j) {
                int e = wrow0 + lk * 4 + j;
                if (e < me) {
                    int b = ent[e] >> 1;
                    out[(size_t)b * VD + col] = acc2[n][j];
                }
            }
        }
    }
}

extern "C" void kernel_launch(void* const* d_in, const int* in_sizes, int n_in,
                              void* d_out, int out_size, void* d_ws, size_t ws_size,
                              hipStream_t stream) {
    (void)in_sizes; (void)n_in; (void)out_size; (void)ws_size;
    const float* hidden   = (const float*)d_in[0];
    const float* rule_emb = (const float*)d_in[1];
    const float* Wq       = (const float*)d_in[2];
    const float* bq       = (const float*)d_in[3];
    const float* Wk       = (const float*)d_in[4];
    const float* W1       = (const float*)d_in[5];
    const float* W2       = (const float*)d_in[6];
    float* out = (float*)d_out;

    char* ws = (char*)d_ws;
    double* Gc             = (double*)(ws + WS_GC);
    int* cnt               = (int*)(ws + WS_CNT);
    unsigned short* list16 = (unsigned short*)(ws + WS_LIST);
    unsigned char* vbyte   = (unsigned char*)(ws + WS_VB);
    unsigned short* W1f    = (unsigned short*)(ws + WS_W1F);
    unsigned short* W2f    = (unsigned short*)(ws + WS_W2F);

    k0_prep<<<1, 256, 0, stream>>>(rule_emb, Wq, bq, Wk, Gc, cnt);
    k0_wfrag<<<672, 256, 0, stream>>>(W1, W2, W1f, W2f);
    k1_select<<<256, 256, 0, stream>>>(hidden, Gc, cnt, list16, vbyte);
    k2_mlp<<<dim3(1024, NR), 256, 0, stream>>>(hidden, W1f, W2f, cnt, list16, vbyte, out);
}